// Round 4
// baseline (269.807 us; speedup 1.0000x reference)
//
#include <hip/hip_runtime.h>
#include <cmath>

typedef short bf16x8 __attribute__((ext_vector_type(8)));
typedef float f32x4 __attribute__((ext_vector_type(4)));

#define T_DIM 1024

__device__ __forceinline__ unsigned short rtn_bf16(float f) {
    unsigned u = __float_as_uint(f);
    return (unsigned short)((u + 0x7FFFu + ((u >> 16) & 1u)) >> 16);
}
// Truncation-based exact 3-limb split (subtracting a truncation is exact in fp32)
__device__ __forceinline__ void split3(float f, unsigned short& h1,
                                       unsigned short& h2, unsigned short& h3) {
    unsigned u = __float_as_uint(f);
    h1 = (unsigned short)(u >> 16);
    float r1 = f - __uint_as_float(u & 0xFFFF0000u);
    unsigned u1 = __float_as_uint(r1);
    h2 = (unsigned short)(u1 >> 16);
    float r2 = r1 - __uint_as_float(u1 & 0xFFFF0000u);
    h3 = rtn_bf16(r2);
}

// ---------------------------------------------------------------------------
// Kernel 0: split w (fp32 [k][n]) into 3 bf16 limbs, TRANSPOSED: wT[n][k].
// ---------------------------------------------------------------------------
__global__ __launch_bounds__(256) void lif_wsplit(const float* __restrict__ w,
                                                  unsigned short* __restrict__ wT1,
                                                  unsigned short* __restrict__ wT2,
                                                  unsigned short* __restrict__ wT3) {
    const int id = blockIdx.x * 256 + threadIdx.x;
    const int k = id >> 8, n = id & 255;
    unsigned short h1, h2, h3;
    split3(w[id], h1, h2, h3);
    const int o = n * 256 + k;
    wT1[o] = h1; wT2[o] = h2; wT3[o] = h3;
}

// ---------------------------------------------------------------------------
// GEMM of one 128(t) x 64(o) tile, K=256, into an LDS x-tile [128][64].
// Wave (ms,ns) computes a 32x32 sub-tile: 2mt x 2nt MFMA frags, 8 kf chunks.
// A fragments loaded DIRECT from global (8 consecutive floats per lane, R3
// pattern), 2-deep prefetch (covers ~900cy HBM under ~2 kf of work).
// B limbs from L2-hot wT, 1-deep prefetch (L2 ~200-300cy).
// Limb values, 6-product order (a1w1,a1w2,a2w1,a2w2,a1w3,a3w1) and ascending
// kf accumulation are IDENTICAL to prior rounds -> bit-identical x.
// ---------------------------------------------------------------------------
__device__ __forceinline__ void gemm_tile(const float* __restrict__ abase,
                                          const unsigned short* __restrict__ wT1,
                                          const unsigned short* __restrict__ wT2,
                                          const unsigned short* __restrict__ wT3,
                                          size_t wbase,
                                          float* __restrict__ xtile,
                                          int ms, int ns, int l15, int quad) {
    f32x4 acc[2][2];
    #pragma unroll
    for (int i = 0; i < 2; ++i)
        #pragma unroll
        for (int j = 0; j < 2; ++j) acc[i][j] = (f32x4){0.f, 0.f, 0.f, 0.f};

    float4 rvP[2][2][2];              // [parity][mt][half] : 2-deep A pipeline
    bf16x8 bv[3][2];                  // 1-deep B pipeline

    #pragma unroll
    for (int mt = 0; mt < 2; ++mt) {  // A for kf=0,1
        const float* ap = abase + (size_t)mt * 16 * 256;
        rvP[0][mt][0] = *(const float4*)(ap);
        rvP[0][mt][1] = *(const float4*)(ap + 4);
        rvP[1][mt][0] = *(const float4*)(ap + 32);
        rvP[1][mt][1] = *(const float4*)(ap + 36);
    }
    #pragma unroll
    for (int nt = 0; nt < 2; ++nt) {  // B for kf=0
        const size_t wo = wbase + (size_t)nt * 16 * 256;
        bv[0][nt] = *(const bf16x8*)(wT1 + wo);
        bv[1][nt] = *(const bf16x8*)(wT2 + wo);
        bv[2][nt] = *(const bf16x8*)(wT3 + wo);
    }

    #pragma unroll
    for (int kf = 0; kf < 8; ++kf) {
        const int par = kf & 1;
        // split this kf's A floats -> 3 limb fragments (registers)
        bf16x8 af[3][2];
        #pragma unroll
        for (int mt = 0; mt < 2; ++mt) {
            const float fv[8] = {rvP[par][mt][0].x, rvP[par][mt][0].y,
                                 rvP[par][mt][0].z, rvP[par][mt][0].w,
                                 rvP[par][mt][1].x, rvP[par][mt][1].y,
                                 rvP[par][mt][1].z, rvP[par][mt][1].w};
            #pragma unroll
            for (int i = 0; i < 8; ++i) {
                unsigned short h1, h2, h3;
                split3(fv[i], h1, h2, h3);
                af[0][mt][i] = (short)h1;
                af[1][mt][i] = (short)h2;
                af[2][mt][i] = (short)h3;
            }
        }
        // snapshot current B, then prefetch: A for kf+2, B for kf+1
        bf16x8 cb[3][2];
        #pragma unroll
        for (int q = 0; q < 3; ++q) { cb[q][0] = bv[q][0]; cb[q][1] = bv[q][1]; }
        if (kf < 6) {
            #pragma unroll
            for (int mt = 0; mt < 2; ++mt) {
                const float* ap = abase + (size_t)mt * 16 * 256 + (kf + 2) * 32;
                rvP[par][mt][0] = *(const float4*)(ap);
                rvP[par][mt][1] = *(const float4*)(ap + 4);
            }
        }
        if (kf < 7) {
            #pragma unroll
            for (int nt = 0; nt < 2; ++nt) {
                const size_t wo = wbase + (size_t)nt * 16 * 256 + (kf + 1) * 32;
                bv[0][nt] = *(const bf16x8*)(wT1 + wo);
                bv[1][nt] = *(const bf16x8*)(wT2 + wo);
                bv[2][nt] = *(const bf16x8*)(wT3 + wo);
            }
        }
        // MFMA clusters (order identical to prior rounds)
        #pragma unroll
        for (int nt = 0; nt < 2; ++nt) {
            #pragma unroll
            for (int mt = 0; mt < 2; ++mt) {
                f32x4 a = acc[mt][nt];
                a = __builtin_amdgcn_mfma_f32_16x16x32_bf16(af[0][mt], cb[0][nt], a, 0, 0, 0);
                a = __builtin_amdgcn_mfma_f32_16x16x32_bf16(af[0][mt], cb[1][nt], a, 0, 0, 0);
                a = __builtin_amdgcn_mfma_f32_16x16x32_bf16(af[1][mt], cb[0][nt], a, 0, 0, 0);
                a = __builtin_amdgcn_mfma_f32_16x16x32_bf16(af[1][mt], cb[1][nt], a, 0, 0, 0);
                a = __builtin_amdgcn_mfma_f32_16x16x32_bf16(af[0][mt], cb[2][nt], a, 0, 0, 0);
                a = __builtin_amdgcn_mfma_f32_16x16x32_bf16(af[2][mt], cb[0][nt], a, 0, 0, 0);
                acc[mt][nt] = a;
            }
        }
    }

    // epilogue -> LDS x-tile. C/D layout: col=l15, row=quad*4+reg
    #pragma unroll
    for (int mt = 0; mt < 2; ++mt)
        #pragma unroll
        for (int nt = 0; nt < 2; ++nt) {
            const int c  = ns * 32 + nt * 16 + l15;
            const int r0 = ms * 32 + mt * 16 + quad * 4;
            #pragma unroll
            for (int reg = 0; reg < 4; ++reg)
                xtile[(r0 + reg) * 64 + c] = acc[mt][nt][reg];
        }
}

// ---------------------------------------------------------------------------
// FUSED kernel: GEMM + LIF scan. 256 blocks (1/CU) x 512 threads (8 waves).
// Block = (b, 64-col o-group). 8 t-tiles of 128 rows, double-buffered in LDS
// (2 x 32 KiB). Round i: all waves GEMM tile i+1 into buf[(i+1)&1]; the
// scanner wave (w==i, rotates) scans tile i from buf[i&1] (64 lanes = 64 o),
// carrying fp64 syn/mem via LDS handoff, streaming U nontemporally. ONE
// barrier per round: scan-i reads and GEMM-(i+1) writes touch different
// buffers; round i+1's overwrite of buf[i&1] is after the barrier.
// Kills the 128 MB xbuf round-trip; scan fp64 latency and split-VALU hide
// under MFMA via 2-waves/SIMD co-issue. Math/order identical -> bit-identical.
// ---------------------------------------------------------------------------
__global__ __launch_bounds__(512) void lif_fused(const float* __restrict__ in,
                                                 const unsigned short* __restrict__ wT1,
                                                 const unsigned short* __restrict__ wT2,
                                                 const unsigned short* __restrict__ wT3,
                                                 float* __restrict__ U,
                                                 double dcy_syn, double dcy_mem,
                                                 double scl_mem) {
    __shared__ float  xs[2][128 * 64];   // 64 KiB x-tile double buffer
    __shared__ double stS[64], stM[64];  // scan state handoff

    const int tid  = threadIdx.x;
    const int blk  = blockIdx.x;
    const int b    = blk >> 2;
    const int og   = (blk & 3) * 64;
    const int w    = tid >> 6;
    const int lane = tid & 63;
    const int l15  = lane & 15;
    const int quad = lane >> 4;
    const int ms   = w >> 1;
    const int ns   = w & 1;

    if (tid < 64) {
        stS[tid] = 0.0; stM[tid] = 0.0;
        U[(size_t)b * T_DIM * 256 + og + tid] = 0.0f;   // U[b][0][o] = 0
    }

    const float* abase = in + ((size_t)b * 1024 + ms * 32 + l15) * 256 + quad * 8;
    const size_t wbase = (size_t)(og + ns * 32 + l15) * 256 + quad * 8;

    // prologue: GEMM tile 0 -> buf0
    gemm_tile(abase, wT1, wT2, wT3, wbase, xs[0], ms, ns, l15, quad);
    __syncthreads();

    #pragma unroll 1
    for (int i = 0; i < 8; ++i) {
        if (i < 7)
            gemm_tile(abase + (size_t)(i + 1) * 128 * 256, wT1, wT2, wT3, wbase,
                      xs[(i + 1) & 1], ms, ns, l15, quad);

        if (w == i) {   // scanner wave for this round (wave-uniform branch)
            double syn = stS[lane], mem = stM[lane];
            const float* xb = &xs[i & 1][0] + lane;
            float* uo = U + (size_t)b * T_DIM * 256 + og + lane;
            const int t0 = i * 128;

            float xwA[8], xwB[8];
            #pragma unroll
            for (int j = 0; j < 8; ++j) xwA[j] = xb[j * 64];

            #pragma unroll 1
            for (int cc = 0; cc < 8; ++cc) {   // 8 x (2 chunks of 8) = 128 t
                const int tb = t0 + cc * 16;
                #pragma unroll
                for (int j = 0; j < 8; ++j) xwB[j] = xb[(cc * 16 + 8 + j) * 64];
                #pragma unroll
                for (int j = 0; j < 8; ++j) {
                    const int t = tb + j;
                    double nm = dcy_mem * mem + scl_mem * syn;
                    if (mem - 1.0 > 0.0) nm = 0.0;
                    syn = dcy_syn * syn + (double)xwA[j];
                    mem = nm;
                    if (t < T_DIM - 1)
                        __builtin_nontemporal_store((float)mem, uo + (size_t)(t + 1) * 256);
                }
                if (cc < 7) {
                    #pragma unroll
                    for (int j = 0; j < 8; ++j) xwA[j] = xb[(cc * 16 + 16 + j) * 64];
                }
                #pragma unroll
                for (int j = 0; j < 8; ++j) {
                    const int t = tb + 8 + j;
                    double nm = dcy_mem * mem + scl_mem * syn;
                    if (mem - 1.0 > 0.0) nm = 0.0;
                    syn = dcy_syn * syn + (double)xwB[j];
                    mem = nm;
                    if (t < T_DIM - 1)
                        __builtin_nontemporal_store((float)mem, uo + (size_t)(t + 1) * 256);
                }
            }
            stS[lane] = syn; stM[lane] = mem;
        }
        __syncthreads();
    }
}

extern "C" void kernel_launch(void* const* d_in, const int* in_sizes, int n_in,
                              void* d_out, int out_size, void* d_ws, size_t ws_size,
                              hipStream_t stream) {
    const float* in = (const float*)d_in[0];   // fp32 [64][1024][256]
    const float* w  = (const float*)d_in[1];   // fp32 [256][256]
    float* U = (float*)d_out;                  // fp32 [64][1024][256]

    const double dcy_mem = exp(-0.001 / (0.01  + 1e-16));
    const double dcy_syn = exp(-0.001 / (0.005 + 1e-16));
    const double scl_mem = 1.0 - dcy_mem;

    // ws layout: wT1|wT2|wT3 (3 x 128 KiB bf16); xbuf no longer needed
    char* ws = (char*)d_ws;
    unsigned short* wT1 = (unsigned short*)ws;
    unsigned short* wT2 = (unsigned short*)(ws + 131072);
    unsigned short* wT3 = (unsigned short*)(ws + 262144);

    lif_wsplit<<<dim3(256), dim3(256), 0, stream>>>(w, wT1, wT2, wT3);
    lif_fused<<<dim3(256), dim3(512), 0, stream>>>(in, wT1, wT2, wT3, U,
                                                   dcy_syn, dcy_mem, scl_mem);
}